// Round 1
// baseline (158.373 us; speedup 1.0000x reference)
//
#include <hip/hip_runtime.h>

#define MB 2
#define NQ 1024
#define NK 1024
#define DXC 256
#define HD 256
#define HH 8
#define DD 32
#define KHC 32
#define KS 8
#define KLEN (NK / KS)
#define SCALE 0.17677669529663687f  // 32^-0.5

// ws layout (float offsets)
#define OFF_QP   0u
#define OFF_KP   524288u
#define OFF_VP   1048576u
#define OFF_AQ   1572864u
#define OFF_BK   1638400u
#define OFF_PART 1703936u            // [16][KS][36][NQ] = 4718592
#define OFF_HO   6422528u            // head_out 524288
#define OFF_TS   6946816u            // tsum 4

// ---------------- projections: x[2048,256] @ W[256,256] -> o[2048,256] -----
__global__ __launch_bounds__(256) void proj_kernel(
    const float* __restrict__ xq, const float* __restrict__ xk, const float* __restrict__ xv,
    const float* __restrict__ Wq, const float* __restrict__ Wk, const float* __restrict__ Wv,
    float* __restrict__ qp, float* __restrict__ kp, float* __restrict__ vp)
{
    const float* x; const float* w; float* o;
    if (blockIdx.z == 0)      { x = xq; w = Wq; o = qp; }
    else if (blockIdx.z == 1) { x = xk; w = Wk; o = kp; }
    else                      { x = xv; w = Wv; o = vp; }

    __shared__ float sA[16][64];  // [kk][r]
    __shared__ float sB[16][64];  // [kk][c]
    const int r0 = blockIdx.x * 64, c0 = blockIdx.y * 64;
    const int t = threadIdx.x;
    const int tx = t & 15, ty = t >> 4;
    float acc[4][4] = {};

    for (int k0 = 0; k0 < DXC; k0 += 16) {
        {   // A tile (transposed store)
            int r = t >> 2;
            int ks4 = (t & 3) * 4;
            float4 v4 = *(const float4*)(x + (size_t)(r0 + r) * DXC + k0 + ks4);
            sA[ks4 + 0][r] = v4.x; sA[ks4 + 1][r] = v4.y;
            sA[ks4 + 2][r] = v4.z; sA[ks4 + 3][r] = v4.w;
        }
        {   // B tile
            int kk = t >> 4;
            int c4 = (t & 15) * 4;
            *(float4*)&sB[kk][c4] = *(const float4*)(w + (size_t)(k0 + kk) * HD + c0 + c4);
        }
        __syncthreads();
        #pragma unroll
        for (int kk = 0; kk < 16; ++kk) {
            float a[4], b[4];
            #pragma unroll
            for (int i = 0; i < 4; ++i) a[i] = sA[kk][ty * 4 + i];
            #pragma unroll
            for (int j = 0; j < 4; ++j) b[j] = sB[kk][tx * 4 + j];
            #pragma unroll
            for (int i = 0; i < 4; ++i)
                #pragma unroll
                for (int j = 0; j < 4; ++j) acc[i][j] += a[i] * b[j];
        }
        __syncthreads();
    }
    #pragma unroll
    for (int i = 0; i < 4; ++i) {
        float4 v4 = { acc[i][0], acc[i][1], acc[i][2], acc[i][3] };
        *(float4*)(o + (size_t)(r0 + ty * 4 + i) * HD + c0 + tx * 4) = v4;
    }
}

// ---------------- aq = tq@Wk1 + bk1 ; bk = tk@Wk1 --------------------------
__global__ __launch_bounds__(256) void prep_kernel(
    const float* __restrict__ tq, const float* __restrict__ tk,
    const float* __restrict__ Wk1, const float* __restrict__ bk1,
    float* __restrict__ aq, float* __restrict__ bk)
{
    int gid = blockIdx.x * 256 + threadIdx.x;
    if (gid < MB * NQ * KHC) {
        int row = gid >> 5, j = gid & 31;
        aq[gid] = tq[row * 2] * Wk1[j] + tq[row * 2 + 1] * Wk1[KHC + j] + bk1[j];
    } else {
        int g = gid - MB * NQ * KHC;
        int row = g >> 5, j = g & 31;
        bk[g] = tk[row * 2] * Wk1[j] + tk[row * 2 + 1] * Wk1[KHC + j];
    }
}

// ---------------- tsum[m*2+c] = sum_k tk[m,k,c] ----------------------------
__global__ __launch_bounds__(256) void tsum_kernel(const float* __restrict__ tk, float* __restrict__ tsum)
{
    __shared__ float red[256];
    int t = threadIdx.x;
    for (int mc = 0; mc < 4; ++mc) {
        int m = mc >> 1, c = mc & 1;
        float s = 0.f;
        for (int k = t; k < NK; k += 256) s += tk[(size_t)(m * NK + k) * 2 + c];
        red[t] = s; __syncthreads();
        for (int off = 128; off > 0; off >>= 1) {
            if (t < off) red[t] += red[t + off];
            __syncthreads();
        }
        if (t == 0) tsum[mc] = red[0];
        __syncthreads();
    }
}

// ---------------- fused attention (split-k, no-max exp) --------------------
__global__ __launch_bounds__(256) void attn_kernel(
    const float* __restrict__ qp, const float* __restrict__ kp, const float* __restrict__ vp,
    const float* __restrict__ aq, const float* __restrict__ bkb, const float* __restrict__ tk,
    const float* __restrict__ Wk2, const float* __restrict__ bk2,
    float* __restrict__ part)
{
    const int mh = blockIdx.z;           // 0..15
    const int m = mh >> 3, h = mh & 7;
    const int q0 = blockIdx.y * 256;     // 0..3
    const int ks = blockIdx.x;           // 0..7
    const int k0 = ks * KLEN;
    const int t = threadIdx.x;
    const int q = q0 + t;

    __shared__ float sK[KLEN][DD];
    __shared__ float sV[KLEN][DD];
    __shared__ float sB[KLEN][KHC];
    __shared__ float sT[KLEN][2];

    {   // cooperative staging
        const float* kbase = kp + (size_t)(m * NK + k0) * HD + h * DD;
        const float* vbase = vp + (size_t)(m * NK + k0) * HD + h * DD;
        const float* bbase = bkb + (size_t)(m * NK + k0) * KHC;
        #pragma unroll
        for (int i = 0; i < 4; ++i) {
            int g = t + i * 256;          // float4 index 0..1023
            int r = g >> 3, c4 = (g & 7) * 4;
            *(float4*)&sK[r][c4] = *(const float4*)(kbase + (size_t)r * HD + c4);
            *(float4*)&sV[r][c4] = *(const float4*)(vbase + (size_t)r * HD + c4);
            *(float4*)(&sB[0][0] + g * 4) = *(const float4*)(bbase + g * 4);
        }
        if (t < 64)
            *(float4*)(&sT[0][0] + t * 4) = *(const float4*)(tk + (size_t)(m * NK + k0) * 2 + t * 4);
    }

    float qreg[DD], aqreg[KHC], w2[KHC];
    {
        const float* qb = qp + (size_t)(m * NQ + q) * HD + h * DD;
        #pragma unroll
        for (int d4 = 0; d4 < 8; ++d4) *(float4*)&qreg[d4 * 4] = *(const float4*)(qb + d4 * 4);
        #pragma unroll
        for (int d = 0; d < DD; ++d) qreg[d] *= SCALE;
        const float* ab = aq + (size_t)(m * NQ + q) * KHC;
        #pragma unroll
        for (int j4 = 0; j4 < 8; ++j4) *(float4*)&aqreg[j4 * 4] = *(const float4*)(ab + j4 * 4);
        #pragma unroll
        for (int j = 0; j < KHC; ++j) w2[j] = Wk2[j * HH + h];
    }
    const float b2 = bk2[h];
    __syncthreads();

    float acc[DD] = {};
    float aT0 = 0.f, aT1 = 0.f, l = 0.f;
    for (int kk = 0; kk < KLEN; ++kk) {
        float s = 0.f;
        #pragma unroll
        for (int d = 0; d < DD; ++d) s += qreg[d] * sK[kk][d];
        float kd = 0.f;
        #pragma unroll
        for (int j = 0; j < KHC; ++j) {
            float hh = aqreg[j] - sB[kk][j];
            kd += fmaxf(hh, 0.f) * w2[j];
        }
        float p = __expf(s + kd + b2);
        l += p;
        #pragma unroll
        for (int d = 0; d < DD; ++d) acc[d] += p * sV[kk][d];
        aT0 += p * sT[kk][0];
        aT1 += p * sT[kk][1];
    }

    // partials layout [mh][ks][36][NQ]
    float* pb = part + ((size_t)(mh * KS + ks) * 36) * NQ + q;
    #pragma unroll
    for (int d = 0; d < DD; ++d) pb[(size_t)d * NQ] = acc[d];
    pb[32u * NQ] = aT0; pb[33u * NQ] = aT1; pb[34u * NQ] = l;
}

// ---------------- combine slices + tq_new ----------------------------------
__global__ __launch_bounds__(256) void combine_kernel(
    const float* __restrict__ part, const float* __restrict__ tq,
    const float* __restrict__ Wphi, const float* __restrict__ bphi,
    const float* __restrict__ tsum,
    float* __restrict__ head_out, float* __restrict__ tq_out)
{
    const int b = blockIdx.x;            // 64 blocks
    const int m = b >> 5;
    const int q0 = (b & 31) * 32;
    const int t = threadIdx.x;
    const int h = t >> 5, ql = t & 31;
    const int q = q0 + ql;
    const int mh = m * HH + h;

    const float* pb = part + ((size_t)(mh * KS)) * 36 * NQ + q;
    float acc[DD] = {};
    float aT0 = 0.f, aT1 = 0.f, l = 0.f;
    for (int s = 0; s < KS; ++s) {
        const float* ps = pb + (size_t)s * 36 * NQ;
        #pragma unroll
        for (int d = 0; d < DD; ++d) acc[d] += ps[(size_t)d * NQ];
        aT0 += ps[32u * NQ]; aT1 += ps[33u * NQ]; l += ps[34u * NQ];
    }
    const float inv = 1.f / l;
    float* ho = head_out + (size_t)(m * NQ + q) * HD + h * DD;
    #pragma unroll
    for (int d4 = 0; d4 < 8; ++d4) {
        float4 v4 = { acc[d4*4]*inv, acc[d4*4+1]*inv, acc[d4*4+2]*inv, acc[d4*4+3]*inv };
        *(float4*)(ho + d4 * 4) = v4;
    }
    const float A0 = aT0 * inv, A1 = aT1 * inv;
    const float tq0 = tq[(size_t)(m * NQ + q) * 2];
    const float tq1 = tq[(size_t)(m * NQ + q) * 2 + 1];
    const float d0 = Wphi[h * 2 + 0] * (tq0 - A0);
    const float d1 = Wphi[h * 2 + 1] * (tq1 - A1);

    __shared__ float sD[8][32][2];
    sD[h][ql][0] = d0; sD[h][ql][1] = d1;
    __syncthreads();
    if (t < 64) {
        int ql2 = t >> 1, c = t & 1;
        float s = 0.f;
        #pragma unroll
        for (int hh2 = 0; hh2 < 8; ++hh2) s += sD[hh2][ql2][c];
        int qg = q0 + ql2;
        float tqv = tq[(size_t)(m * NQ + qg) * 2 + c];
        const float invnk = 1.f / (float)NK;
        float val = tqv + s * invnk + bphi[c] * (tqv - tsum[m * 2 + c] * invnk);
        tq_out[(size_t)(m * NQ + qg) * 2 + c] = val;
    }
}

// ---------------- out = head_out @ Wo + bo ---------------------------------
__global__ __launch_bounds__(256) void outproj_kernel(
    const float* __restrict__ xin, const float* __restrict__ w,
    const float* __restrict__ bias, float* __restrict__ o)
{
    __shared__ float sA[16][64];
    __shared__ float sB[16][64];
    const int r0 = blockIdx.x * 64, c0 = blockIdx.y * 64;
    const int t = threadIdx.x;
    const int tx = t & 15, ty = t >> 4;
    float acc[4][4] = {};

    for (int k0 = 0; k0 < HD; k0 += 16) {
        {
            int r = t >> 2;
            int ks4 = (t & 3) * 4;
            float4 v4 = *(const float4*)(xin + (size_t)(r0 + r) * HD + k0 + ks4);
            sA[ks4 + 0][r] = v4.x; sA[ks4 + 1][r] = v4.y;
            sA[ks4 + 2][r] = v4.z; sA[ks4 + 3][r] = v4.w;
        }
        {
            int kk = t >> 4;
            int c4 = (t & 15) * 4;
            *(float4*)&sB[kk][c4] = *(const float4*)(w + (size_t)(k0 + kk) * DXC + c0 + c4);
        }
        __syncthreads();
        #pragma unroll
        for (int kk = 0; kk < 16; ++kk) {
            float a[4], b[4];
            #pragma unroll
            for (int i = 0; i < 4; ++i) a[i] = sA[kk][ty * 4 + i];
            #pragma unroll
            for (int j = 0; j < 4; ++j) b[j] = sB[kk][tx * 4 + j];
            #pragma unroll
            for (int i = 0; i < 4; ++i)
                #pragma unroll
                for (int j = 0; j < 4; ++j) acc[i][j] += a[i] * b[j];
        }
        __syncthreads();
    }
    #pragma unroll
    for (int i = 0; i < 4; ++i) {
        float4 v4 = { acc[i][0] + bias[c0 + tx * 4],
                      acc[i][1] + bias[c0 + tx * 4 + 1],
                      acc[i][2] + bias[c0 + tx * 4 + 2],
                      acc[i][3] + bias[c0 + tx * 4 + 3] };
        *(float4*)(o + (size_t)(r0 + ty * 4 + i) * DXC + c0 + tx * 4) = v4;
    }
}

extern "C" void kernel_launch(void* const* d_in, const int* in_sizes, int n_in,
                              void* d_out, int out_size, void* d_ws, size_t ws_size,
                              hipStream_t stream)
{
    const float* xq   = (const float*)d_in[0];
    const float* xk   = (const float*)d_in[1];
    const float* xv   = (const float*)d_in[2];
    const float* tq   = (const float*)d_in[3];
    const float* tk   = (const float*)d_in[4];
    const float* Wq   = (const float*)d_in[5];
    const float* Wk   = (const float*)d_in[6];
    const float* Wv   = (const float*)d_in[7];
    const float* Wo   = (const float*)d_in[8];
    const float* bo   = (const float*)d_in[9];
    const float* Wk1  = (const float*)d_in[10];
    const float* bk1  = (const float*)d_in[11];
    const float* Wk2  = (const float*)d_in[12];
    const float* bk2  = (const float*)d_in[13];
    const float* Wphi = (const float*)d_in[14];
    const float* bphi = (const float*)d_in[15];

    float* wsf  = (float*)d_ws;
    float* qp   = wsf + OFF_QP;
    float* kp   = wsf + OFF_KP;
    float* vp   = wsf + OFF_VP;
    float* aqb  = wsf + OFF_AQ;
    float* bkb  = wsf + OFF_BK;
    float* part = wsf + OFF_PART;
    float* ho   = wsf + OFF_HO;
    float* ts   = wsf + OFF_TS;

    float* out    = (float*)d_out;
    float* tq_out = out + (size_t)MB * NQ * HD;

    hipLaunchKernelGGL(proj_kernel, dim3(32, 4, 3), dim3(256), 0, stream,
                       xq, xk, xv, Wq, Wk, Wv, qp, kp, vp);
    hipLaunchKernelGGL(prep_kernel, dim3(512), dim3(256), 0, stream,
                       tq, tk, Wk1, bk1, aqb, bkb);
    hipLaunchKernelGGL(tsum_kernel, dim3(1), dim3(256), 0, stream, tk, ts);
    hipLaunchKernelGGL(attn_kernel, dim3(KS, 4, 16), dim3(256), 0, stream,
                       qp, kp, vp, aqb, bkb, tk, Wk2, bk2, part);
    hipLaunchKernelGGL(combine_kernel, dim3(64), dim3(256), 0, stream,
                       part, tq, Wphi, bphi, ts, ho, tq_out);
    hipLaunchKernelGGL(outproj_kernel, dim3(32, 4), dim3(256), 0, stream,
                       ho, Wo, bo, out);
}

// Round 2
// 99.164 us; speedup vs baseline: 1.5971x; 1.5971x over previous
//
#include <hip/hip_runtime.h>
#include <hip/hip_bf16.h>

#define MB 2
#define NQ 1024
#define NK 1024
#define DXC 256
#define HD 256
#define HH 8
#define DD 32
#define KHC 32
#define SCALE 0.17677669529663687f
#define LOG2E 1.4426950408889634f
#define QSCALE 0.25503472301046627f   // SCALE*LOG2E

#define QB 32
#define KB 32
#define KSPLIT 8
#define KL (NK / KSPLIT)      // 128
#define NCHUNK (KL / KB)      // 4

// ws layout (float offsets)
#define QPB_F   0u            // bf16 q (scaled by QSCALE)  [2][1024][256] : 262144 floats
#define KPB_F   262144u       // bf16 k                     [2][1024][256]
#define VPT_F   524288u       // bf16 v TRANSPOSED          [2][256][1024]
#define AQ_F    786432u       // f32 aq = tq@Wk1+bk1        [2][1024][32]
#define BK_F    851968u       // f32 bk = tk@Wk1            [2][1024][32]
#define TS_F    917504u       // f32 tsum[4]
#define PART_F  917512u       // f32 [16mh][8ks][1024q][40] = 5242880
#define HO_F    6160392u      // f32 head_out [2][1024][256]

typedef float f32x4 __attribute__((ext_vector_type(4)));
typedef short bf16x8 __attribute__((ext_vector_type(8)));

#define MFMA(a, b, c) __builtin_amdgcn_mfma_f32_16x16x32_bf16(a, b, c, 0, 0, 0)

#if defined(__has_builtin)
#if __has_builtin(__builtin_amdgcn_exp2f)
#define EXP2(x) __builtin_amdgcn_exp2f(x)
#else
#define EXP2(x) exp2f(x)
#endif
#else
#define EXP2(x) exp2f(x)
#endif

__device__ __forceinline__ float bf2f(ushort x) {
    return __uint_as_float(((uint)x) << 16);
}
__device__ __forceinline__ ushort f2bf(float f) {
    __hip_bfloat16 h = __float2bfloat16(f);
    return __builtin_bit_cast(ushort, h);
}

// ---------------- projections: x[2048,256] @ W[256,256] -> bf16 outputs ----
__global__ __launch_bounds__(256) void proj_kernel(
    const float* __restrict__ xq, const float* __restrict__ xk, const float* __restrict__ xv,
    const float* __restrict__ Wq, const float* __restrict__ Wk, const float* __restrict__ Wv,
    ushort* __restrict__ qpb, ushort* __restrict__ kpb, ushort* __restrict__ vpt)
{
    const float* x; const float* w;
    const int z = blockIdx.z;
    if (z == 0)      { x = xq; w = Wq; }
    else if (z == 1) { x = xk; w = Wk; }
    else             { x = xv; w = Wv; }

    __shared__ float sA[16][64];
    __shared__ float sB[16][64];
    const int r0 = blockIdx.x * 64, c0 = blockIdx.y * 64;
    const int t = threadIdx.x;
    const int tx = t & 15, ty = t >> 4;
    float acc[4][4] = {};

    for (int k0 = 0; k0 < DXC; k0 += 16) {
        {
            int r = t >> 2;
            int ks4 = (t & 3) * 4;
            float4 v4 = *(const float4*)(x + (size_t)(r0 + r) * DXC + k0 + ks4);
            sA[ks4 + 0][r] = v4.x; sA[ks4 + 1][r] = v4.y;
            sA[ks4 + 2][r] = v4.z; sA[ks4 + 3][r] = v4.w;
        }
        {
            int kk = t >> 4;
            int c4 = (t & 15) * 4;
            *(float4*)&sB[kk][c4] = *(const float4*)(w + (size_t)(k0 + kk) * HD + c0 + c4);
        }
        __syncthreads();
        #pragma unroll
        for (int kk = 0; kk < 16; ++kk) {
            float a[4], b[4];
            #pragma unroll
            for (int i = 0; i < 4; ++i) a[i] = sA[kk][ty * 4 + i];
            #pragma unroll
            for (int j = 0; j < 4; ++j) b[j] = sB[kk][tx * 4 + j];
            #pragma unroll
            for (int i = 0; i < 4; ++i)
                #pragma unroll
                for (int j = 0; j < 4; ++j) acc[i][j] += a[i] * b[j];
        }
        __syncthreads();
    }
    #pragma unroll
    for (int i = 0; i < 4; ++i) {
        #pragma unroll
        for (int j = 0; j < 4; ++j) {
            int row = r0 + ty * 4 + i, col = c0 + tx * 4 + j;
            float v = acc[i][j];
            if (z == 0)      qpb[(size_t)row * HD + col] = f2bf(v * QSCALE);
            else if (z == 1) kpb[(size_t)row * HD + col] = f2bf(v);
            else             vpt[(size_t)(row >> 10) * (HD * NK) + (size_t)col * NK + (row & 1023)] = f2bf(v);
        }
    }
}

// ---------------- aq = tq@Wk1 + bk1 ; bk = tk@Wk1 --------------------------
__global__ __launch_bounds__(256) void prep_kernel(
    const float* __restrict__ tq, const float* __restrict__ tk,
    const float* __restrict__ Wk1, const float* __restrict__ bk1,
    float* __restrict__ aqg, float* __restrict__ bkg)
{
    int gid = blockIdx.x * 256 + threadIdx.x;
    if (gid < MB * NQ * KHC) {
        int row = gid >> 5, j = gid & 31;
        aqg[gid] = tq[row * 2] * Wk1[j] + tq[row * 2 + 1] * Wk1[KHC + j] + bk1[j];
    } else {
        int g = gid - MB * NQ * KHC;
        int row = g >> 5, j = g & 31;
        bkg[g] = tk[row * 2] * Wk1[j] + tk[row * 2 + 1] * Wk1[KHC + j];
    }
}

// ---------------- tsum[m*2+c] = sum_k tk[m,k,c] ----------------------------
__global__ __launch_bounds__(256) void tsum_kernel(const float* __restrict__ tk, float* __restrict__ tsum)
{
    __shared__ float red[256];
    int t = threadIdx.x;
    for (int mc = 0; mc < 4; ++mc) {
        int m = mc >> 1, c = mc & 1;
        float s = 0.f;
        for (int k = t; k < NK; k += 256) s += tk[(size_t)(m * NK + k) * 2 + c];
        red[t] = s; __syncthreads();
        for (int off = 128; off > 0; off >>= 1) {
            if (t < off) red[t] += red[t + off];
            __syncthreads();
        }
        if (t == 0) tsum[mc] = red[0];
        __syncthreads();
    }
}

// ---------------- fused attention v2: head-shared, MFMA --------------------
__global__ __launch_bounds__(256, 2) void attn_kernel(
    const ushort* __restrict__ qpb, const ushort* __restrict__ kpb, const ushort* __restrict__ vpt,
    const float* __restrict__ aqg, const float* __restrict__ bkg, const float* __restrict__ tk,
    const float* __restrict__ Wk2, const float* __restrict__ bk2,
    float* __restrict__ part)
{
    const int ks = blockIdx.x;         // 0..7
    const int qt = blockIdx.y;         // 0..31
    const int m  = blockIdx.z;         // 0..1
    const int q0 = qt * QB;
    const int kbase = ks * KL;
    const int t = threadIdx.x;
    const int wid = t >> 6;            // wave 0..3
    const int l = t & 63;
    const int g = l >> 4;              // 0..3
    const int c16 = l & 15;

    __shared__ ushort sK[32][264];     // K chunk: [k][h*32+d], pad 8
    __shared__ ushort sVT[8][32][32];  // V^T: [h][d][k]
    __shared__ ushort sText[16][32];   // ext B rows: [col][k]; col0=tk0,1=tk1,2=ones
    __shared__ ushort sBK[32][32];     // bk chunk bf16 [k][j]
    __shared__ ushort sAQ[32][32];     // aq tile bf16 [q][j]
    __shared__ ushort sW2T[16][32];    // Wk2^T * LOG2E [h][j]
    __shared__ ushort sKD[8][32][34];  // kd bf16 [h][k][q], q-pad 2
    __shared__ ushort sP[4][32][32];   // per-wave P tile [q][k]

    // ---- once-per-block staging ----
    for (int idx = t; idx < 512; idx += 256) {
        int h = idx >> 5, j = idx & 31;
        float v = (h < HH) ? Wk2[j * HH + h] * LOG2E : 0.f;
        sW2T[h][j] = f2bf(v);
    }
    for (int idx = t; idx < 448; idx += 256) {
        int r = 2 + (idx >> 5), j = idx & 31;
        sText[r][j] = (r == 2) ? (ushort)0x3F80 : (ushort)0;
    }
    {
        int q = t >> 3, j0 = (t & 7) * 4;
        float4 v4 = *(const float4*)(aqg + (size_t)(m * NQ + q0 + q) * KHC + j0);
        uint2 pk;
        pk.x = (uint)f2bf(v4.x) | ((uint)f2bf(v4.y) << 16);
        pk.y = (uint)f2bf(v4.z) | ((uint)f2bf(v4.w) << 16);
        *(uint2*)&sAQ[q][j0] = pk;
    }

    // persistent Q fragments (B-operand): [head][qfrag]
    bf16x8 qb[2][2];
    #pragma unroll
    for (int hh = 0; hh < 2; ++hh)
        #pragma unroll
        for (int qf = 0; qf < 2; ++qf)
            qb[hh][qf] = *(const bf16x8*)(qpb + (size_t)(m * NQ + q0 + qf * 16 + c16) * HD
                                              + (wid * 2 + hh) * DD + g * 8);
    const float b2l = (c16 < HH) ? bk2[c16] * LOG2E : 0.f;

    __syncthreads();
    bf16x8 w2f = *(const bf16x8*)&sW2T[c16][g * 8];

    f32x4 oacc[2][2][3];
    #pragma unroll
    for (int a = 0; a < 2; ++a)
        #pragma unroll
        for (int b = 0; b < 2; ++b)
            #pragma unroll
            for (int c = 0; c < 3; ++c)
                oacc[a][b][c] = (f32x4){0.f, 0.f, 0.f, 0.f};

    for (int ch = 0; ch < NCHUNK; ++ch) {
        const int k0 = kbase + ch * KB;
        __syncthreads();   // previous chunk fully consumed
        // ---- stage chunk ----
        {   // K: thread t -> row t>>3, 64B segment (t&7)
            int row = t >> 3, seg = t & 7;
            const uint4* src = (const uint4*)(kpb + (size_t)(m * NK + k0 + row) * HD + seg * 32);
            uint4* dst = (uint4*)&sK[row][seg * 32];
            #pragma unroll
            for (int i = 0; i < 4; ++i) dst[i] = src[i];
        }
        {   // V^T: thread t -> (h,d) row, 64B, rotated segments
            int h = t >> 5, d = t & 31;
            const uint4* src = (const uint4*)(vpt + (size_t)m * (HD * NK) + (size_t)(h * DD + d) * NK + k0);
            uint4* dst = (uint4*)&sVT[h][d][0];
            #pragma unroll
            for (int i = 0; i < 4; ++i) { int ii = (i + t) & 3; dst[ii] = src[ii]; }
        }
        {   // bk chunk -> bf16
            int k = t >> 3, j0 = (t & 7) * 4;
            float4 v4 = *(const float4*)(bkg + (size_t)(m * NK + k0 + k) * KHC + j0);
            uint2 pk;
            pk.x = (uint)f2bf(v4.x) | ((uint)f2bf(v4.y) << 16);
            pk.y = (uint)f2bf(v4.z) | ((uint)f2bf(v4.w) << 16);
            *(uint2*)&sBK[k][j0] = pk;
        }
        if (t < 32) {   // tk rows of ext tile
            float2 tv = *(const float2*)(tk + (size_t)(m * NK + k0 + t) * 2);
            sText[0][t] = f2bf(tv.x);
            sText[1][t] = f2bf(tv.y);
        }
        __syncthreads();

        // ---- kd phase: kd[k][h] = relu(aq-bk)@(Wk2*LOG2E) + b2*LOG2E via MFMA
        #pragma unroll
        for (int qi = 0; qi < 8; ++qi) {
            int q = wid * 8 + qi;
            bf16x8 aqv = *(const bf16x8*)&sAQ[q][g * 8];
            float aqf[8];
            #pragma unroll
            for (int i = 0; i < 8; ++i) aqf[i] = bf2f((ushort)aqv[i]);
            #pragma unroll
            for (int kh = 0; kh < 2; ++kh) {
                bf16x8 bkv = *(const bf16x8*)&sBK[kh * 16 + c16][g * 8];
                union { bf16x8 v; uint u[4]; } af;
                #pragma unroll
                for (int w = 0; w < 4; ++w) {
                    float h0 = fmaxf(aqf[2 * w]     - bf2f((ushort)bkv[2 * w]),     0.f);
                    float h1 = fmaxf(aqf[2 * w + 1] - bf2f((ushort)bkv[2 * w + 1]), 0.f);
                    af.u[w] = (uint)f2bf(h0) | ((uint)f2bf(h1) << 16);
                }
                f32x4 c = {b2l, b2l, b2l, b2l};
                c = MFMA(af.v, w2f, c);
                if (c16 < HH) {
                    #pragma unroll
                    for (int r = 0; r < 4; ++r)
                        sKD[c16][kh * 16 + g * 4 + r][q] = f2bf(c[r]);
                }
            }
        }
        __syncthreads();

        // ---- per-head: S^T = K.Q^T, +kd, exp2, P->LDS, PV MFMA ----
        #pragma unroll
        for (int hh = 0; hh < 2; ++hh) {
            int h = wid * 2 + hh;
            bf16x8 ka[2];
            ka[0] = *(const bf16x8*)&sK[c16][h * DD + g * 8];
            ka[1] = *(const bf16x8*)&sK[16 + c16][h * DD + g * 8];
            #pragma unroll
            for (int kf = 0; kf < 2; ++kf) {
                #pragma unroll
                for (int qf = 0; qf < 2; ++qf) {
                    f32x4 s = MFMA(ka[kf], qb[hh][qf], ((f32x4){0.f, 0.f, 0.f, 0.f}));
                    float p[4];
                    #pragma unroll
                    for (int r = 0; r < 4; ++r) {
                        float kd = bf2f(sKD[h][kf * 16 + g * 4 + r][qf * 16 + c16]);
                        p[r] = EXP2(s[r] + kd);
                    }
                    uint pk0 = (uint)f2bf(p[0]) | ((uint)f2bf(p[1]) << 16);
                    uint pk1 = (uint)f2bf(p[2]) | ((uint)f2bf(p[3]) << 16);
                    *(uint*)&sP[wid][qf * 16 + c16][kf * 16 + g * 4]     = pk0;
                    *(uint*)&sP[wid][qf * 16 + c16][kf * 16 + g * 4 + 2] = pk1;
                }
            }
            #pragma unroll
            for (int qf = 0; qf < 2; ++qf) {
                bf16x8 pa = *(const bf16x8*)&sP[wid][qf * 16 + c16][g * 8];
                #pragma unroll
                for (int nf = 0; nf < 3; ++nf) {
                    bf16x8 vb = (nf < 2) ? *(const bf16x8*)&sVT[h][nf * 16 + c16][g * 8]
                                         : *(const bf16x8*)&sText[c16][g * 8];
                    oacc[hh][qf][nf] = MFMA(pa, vb, oacc[hh][qf][nf]);
                }
            }
        }
    }

    // ---- write partials: [mh][ks][q][40]: 0..31 = O, 32=aT0, 33=aT1, 34=l
    #pragma unroll
    for (int hh = 0; hh < 2; ++hh) {
        int mh = m * HH + wid * 2 + hh;
        #pragma unroll
        for (int qf = 0; qf < 2; ++qf) {
            #pragma unroll
            for (int r = 0; r < 4; ++r) {
                int q = q0 + qf * 16 + g * 4 + r;
                size_t row = ((size_t)(mh * KSPLIT + ks) * NQ + q) * 40;
                part[row + c16]      = oacc[hh][qf][0][r];
                part[row + 16 + c16] = oacc[hh][qf][1][r];
                if (c16 < 3) part[row + 32 + c16] = oacc[hh][qf][2][r];
            }
        }
    }
}

// ---------------- combine slices + tq_new ----------------------------------
__global__ __launch_bounds__(256) void combine_kernel(
    const float* __restrict__ part, const float* __restrict__ tq,
    const float* __restrict__ Wphi, const float* __restrict__ bphi,
    const float* __restrict__ tsum,
    float* __restrict__ head_out, float* __restrict__ tq_out)
{
    const int b = blockIdx.x;            // 64 blocks
    const int m = b >> 5;
    const int q0 = (b & 31) * 32;
    const int t = threadIdx.x;
    const int h = t >> 5, ql = t & 31;
    const int q = q0 + ql;
    const int mh = m * HH + h;

    float acc[DD] = {};
    float aT0 = 0.f, aT1 = 0.f, lsum = 0.f;
    for (int s = 0; s < KSPLIT; ++s) {
        const float* ps = part + ((size_t)(mh * KSPLIT + s) * NQ + q) * 40;
        #pragma unroll
        for (int d4 = 0; d4 < 8; ++d4) {
            float4 v = *(const float4*)(ps + d4 * 4);
            acc[d4 * 4] += v.x; acc[d4 * 4 + 1] += v.y;
            acc[d4 * 4 + 2] += v.z; acc[d4 * 4 + 3] += v.w;
        }
        aT0 += ps[32]; aT1 += ps[33]; lsum += ps[34];
    }
    const float inv = 1.f / lsum;
    float* ho = head_out + (size_t)(m * NQ + q) * HD + h * DD;
    #pragma unroll
    for (int d4 = 0; d4 < 8; ++d4) {
        float4 v4 = { acc[d4*4]*inv, acc[d4*4+1]*inv, acc[d4*4+2]*inv, acc[d4*4+3]*inv };
        *(float4*)(ho + d4 * 4) = v4;
    }
    const float A0 = aT0 * inv, A1 = aT1 * inv;
    const float tq0 = tq[(size_t)(m * NQ + q) * 2];
    const float tq1 = tq[(size_t)(m * NQ + q) * 2 + 1];
    const float d0 = Wphi[h * 2 + 0] * (tq0 - A0);
    const float d1 = Wphi[h * 2 + 1] * (tq1 - A1);

    __shared__ float sD[8][32][2];
    sD[h][ql][0] = d0; sD[h][ql][1] = d1;
    __syncthreads();
    if (t < 64) {
        int ql2 = t >> 1, c = t & 1;
        float s = 0.f;
        #pragma unroll
        for (int hh2 = 0; hh2 < 8; ++hh2) s += sD[hh2][ql2][c];
        int qg = q0 + ql2;
        float tqv = tq[(size_t)(m * NQ + qg) * 2 + c];
        const float invnk = 1.f / (float)NK;
        float val = tqv + s * invnk + bphi[c] * (tqv - tsum[m * 2 + c] * invnk);
        tq_out[(size_t)(m * NQ + qg) * 2 + c] = val;
    }
}

// ---------------- out = head_out @ Wo + bo ---------------------------------
__global__ __launch_bounds__(256) void outproj_kernel(
    const float* __restrict__ xin, const float* __restrict__ w,
    const float* __restrict__ bias, float* __restrict__ o)
{
    __shared__ float sA[16][64];
    __shared__ float sB[16][64];
    const int r0 = blockIdx.x * 64, c0 = blockIdx.y * 64;
    const int t = threadIdx.x;
    const int tx = t & 15, ty = t >> 4;
    float acc[4][4] = {};

    for (int k0 = 0; k0 < HD; k0 += 16) {
        {
            int r = t >> 2;
            int ks4 = (t & 3) * 4;
            float4 v4 = *(const float4*)(xin + (size_t)(r0 + r) * HD + k0 + ks4);
            sA[ks4 + 0][r] = v4.x; sA[ks4 + 1][r] = v4.y;
            sA[ks4 + 2][r] = v4.z; sA[ks4 + 3][r] = v4.w;
        }
        {
            int kk = t >> 4;
            int c4 = (t & 15) * 4;
            *(float4*)&sB[kk][c4] = *(const float4*)(w + (size_t)(k0 + kk) * DXC + c0 + c4);
        }
        __syncthreads();
        #pragma unroll
        for (int kk = 0; kk < 16; ++kk) {
            float a[4], b[4];
            #pragma unroll
            for (int i = 0; i < 4; ++i) a[i] = sA[kk][ty * 4 + i];
            #pragma unroll
            for (int j = 0; j < 4; ++j) b[j] = sB[kk][tx * 4 + j];
            #pragma unroll
            for (int i = 0; i < 4; ++i)
                #pragma unroll
                for (int j = 0; j < 4; ++j) acc[i][j] += a[i] * b[j];
        }
        __syncthreads();
    }
    #pragma unroll
    for (int i = 0; i < 4; ++i) {
        float4 v4 = { acc[i][0] + bias[c0 + tx * 4],
                      acc[i][1] + bias[c0 + tx * 4 + 1],
                      acc[i][2] + bias[c0 + tx * 4 + 2],
                      acc[i][3] + bias[c0 + tx * 4 + 3] };
        *(float4*)(o + (size_t)(r0 + ty * 4 + i) * DXC + c0 + tx * 4) = v4;
    }
}

extern "C" void kernel_launch(void* const* d_in, const int* in_sizes, int n_in,
                              void* d_out, int out_size, void* d_ws, size_t ws_size,
                              hipStream_t stream)
{
    const float* xq   = (const float*)d_in[0];
    const float* xk   = (const float*)d_in[1];
    const float* xv   = (const float*)d_in[2];
    const float* tq   = (const float*)d_in[3];
    const float* tk   = (const float*)d_in[4];
    const float* Wq   = (const float*)d_in[5];
    const float* Wk   = (const float*)d_in[6];
    const float* Wv   = (const float*)d_in[7];
    const float* Wo   = (const float*)d_in[8];
    const float* bo   = (const float*)d_in[9];
    const float* Wk1  = (const float*)d_in[10];
    const float* bk1  = (const float*)d_in[11];
    const float* Wk2  = (const float*)d_in[12];
    const float* bk2  = (const float*)d_in[13];
    const float* Wphi = (const float*)d_in[14];
    const float* bphi = (const float*)d_in[15];

    float* wsf = (float*)d_ws;
    ushort* qpb = (ushort*)(wsf + QPB_F);
    ushort* kpb = (ushort*)(wsf + KPB_F);
    ushort* vpt = (ushort*)(wsf + VPT_F);
    float* aqg  = wsf + AQ_F;
    float* bkg  = wsf + BK_F;
    float* ts   = wsf + TS_F;
    float* part = wsf + PART_F;
    float* ho   = wsf + HO_F;

    float* out    = (float*)d_out;
    float* tq_out = out + (size_t)MB * NQ * HD;

    hipLaunchKernelGGL(proj_kernel, dim3(32, 4, 3), dim3(256), 0, stream,
                       xq, xk, xv, Wq, Wk, Wv, qpb, kpb, vpt);
    hipLaunchKernelGGL(prep_kernel, dim3(512), dim3(256), 0, stream,
                       tq, tk, Wk1, bk1, aqg, bkg);
    hipLaunchKernelGGL(tsum_kernel, dim3(1), dim3(256), 0, stream, tk, ts);
    hipLaunchKernelGGL(attn_kernel, dim3(KSPLIT, NQ / QB, MB), dim3(256), 0, stream,
                       qpb, kpb, vpt, aqg, bkg, tk, Wk2, bk2, part);
    hipLaunchKernelGGL(combine_kernel, dim3(64), dim3(256), 0, stream,
                       part, tq, Wphi, bphi, ts, ho, tq_out);
    hipLaunchKernelGGL(outproj_kernel, dim3(32, 4), dim3(256), 0, stream,
                       ho, Wo, bo, out);
}

// Round 5
// 81.333 us; speedup vs baseline: 1.9472x; 1.2192x over previous
//
#include <hip/hip_runtime.h>
#include <hip/hip_bf16.h>

#define MB 2
#define NQ 1024
#define NK 1024
#define DXC 256
#define HD 256
#define HH 8
#define DD 32
#define KHC 32
#define SCALE 0.17677669529663687f
#define LOG2E 1.4426950408889634f
#define QSCALE 0.25503472301046627f   // SCALE*LOG2E

#define QB 32
#define KB 32
#define KSPLIT 8
#define KL (NK / KSPLIT)      // 128
#define NCHUNK (KL / KB)      // 4

// ws layout (float offsets)
#define QPB_F   0u            // bf16 q (scaled QSCALE)  [2][1024][256]
#define KPB_F   262144u       // bf16 k
#define VPT_F   524288u       // bf16 v^T [2][256][1024]
#define WT_F    786432u       // bf16 W^T x4 mats [4][256 col][256 k]
#define AQH_F   917504u       // f16 aq [2][1024][32]
#define BKH_F   950272u       // f16 bk [2][1024][32]
#define TS_F    983040u       // f32 tsum[4] (+pad)
#define PART_F  983048u       // f32 [16mh][8ks][1024q][36]
#define HOB_F   5701640u      // bf16 head_out [2][1024][256]

typedef float f32x4 __attribute__((ext_vector_type(4)));
typedef short bf16x8 __attribute__((ext_vector_type(8)));
typedef _Float16 f16x8 __attribute__((ext_vector_type(8)));
typedef _Float16 f16x2 __attribute__((ext_vector_type(2)));

#define MFMA(a, b, c)   __builtin_amdgcn_mfma_f32_16x16x32_bf16(a, b, c, 0, 0, 0)
#define MFMA16(a, b, c) __builtin_amdgcn_mfma_f32_16x16x32_f16(a, b, c, 0, 0, 0)
#define EXP2(x) exp2f(x)

// sKD geometry: [h][q][k] f16, k-stride 36, plane stride 1160
#define KDQ 36
#define KDH 1160

__device__ __forceinline__ float bf2f(ushort x) {
    return __uint_as_float(((uint)x) << 16);
}
__device__ __forceinline__ ushort f2bf(float f) {
    __hip_bfloat16 h = __float2bfloat16(f);
    return __builtin_bit_cast(ushort, h);
}
__device__ __forceinline__ ushort f2h(float f) {
    _Float16 h = (_Float16)f;
    return __builtin_bit_cast(ushort, h);
}

union Bf16x8 { bf16x8 v; ushort u[8]; uint d[4]; };

// ---------------- W -> W^T bf16 (4 matrices, all 256x256) ------------------
__global__ __launch_bounds__(256) void wconv_kernel(
    const float* __restrict__ Wq, const float* __restrict__ Wk,
    const float* __restrict__ Wv, const float* __restrict__ Wo,
    ushort* __restrict__ wt)
{
    const int mat = blockIdx.z;
    const float* W = (mat == 0) ? Wq : (mat == 1) ? Wk : (mat == 2) ? Wv : Wo;
    const int k0 = blockIdx.x * 64, c0 = blockIdx.y * 64;
    const int t = threadIdx.x;
    __shared__ float sW[64][65];
    #pragma unroll
    for (int i = 0; i < 4; ++i) {
        int flat = i * 1024 + t * 4;
        int r = flat >> 6, c = flat & 63;
        float4 v4 = *(const float4*)(W + (size_t)(k0 + r) * 256 + c0 + c);
        sW[r][c] = v4.x; sW[r][c + 1] = v4.y; sW[r][c + 2] = v4.z; sW[r][c + 3] = v4.w;
    }
    __syncthreads();
    #pragma unroll
    for (int i = 0; i < 4; ++i) {
        int flat = i * 1024 + t * 4;
        int cc = flat >> 6, kk = flat & 63;
        uint2 pk;
        pk.x = (uint)f2bf(sW[kk][cc])     | ((uint)f2bf(sW[kk + 1][cc]) << 16);
        pk.y = (uint)f2bf(sW[kk + 2][cc]) | ((uint)f2bf(sW[kk + 3][cc]) << 16);
        *(uint2*)(wt + (size_t)mat * 65536 + (size_t)(c0 + cc) * 256 + k0 + kk) = pk;
    }
}

// ---------------- projections via MFMA: x f32 -> q/k/v bf16 ----------------
__global__ __launch_bounds__(256) void projm_kernel(
    const float* __restrict__ xq, const float* __restrict__ xk, const float* __restrict__ xv,
    const ushort* __restrict__ wt,
    ushort* __restrict__ qpb, ushort* __restrict__ kpb, ushort* __restrict__ vpt)
{
    const int z = blockIdx.y;
    const float* x = (z == 0) ? xq : (z == 1) ? xk : xv;
    const ushort* wz = wt + (size_t)z * 65536;
    const int r0 = blockIdx.x * 32;
    const int t = threadIdx.x;
    const int wid = t >> 6, l = t & 63, g = l >> 4, c16 = l & 15;
    const int wr = (wid >> 1) * 16, wc = (wid & 1) * 128;
    const int row = r0 + wr + c16;

    f32x4 acc[8];
    #pragma unroll
    for (int i = 0; i < 8; ++i) acc[i] = (f32x4){0.f, 0.f, 0.f, 0.f};

    for (int k0 = 0; k0 < DXC; k0 += 32) {
        const float* xr = x + (size_t)row * DXC + k0 + g * 8;
        float4 a0 = *(const float4*)xr;
        float4 a1 = *(const float4*)(xr + 4);
        Bf16x8 af;
        af.d[0] = (uint)f2bf(a0.x) | ((uint)f2bf(a0.y) << 16);
        af.d[1] = (uint)f2bf(a0.z) | ((uint)f2bf(a0.w) << 16);
        af.d[2] = (uint)f2bf(a1.x) | ((uint)f2bf(a1.y) << 16);
        af.d[3] = (uint)f2bf(a1.z) | ((uint)f2bf(a1.w) << 16);
        #pragma unroll
        for (int cf = 0; cf < 8; ++cf) {
            bf16x8 bf = *(const bf16x8*)(wz + (size_t)(wc + cf * 16 + c16) * 256 + k0 + g * 8);
            acc[cf] = MFMA(af.v, bf, acc[cf]);
        }
    }
    #pragma unroll
    for (int cf = 0; cf < 8; ++cf) {
        #pragma unroll
        for (int r = 0; r < 4; ++r) {
            int orow = r0 + wr + g * 4 + r;
            int col = wc + cf * 16 + c16;
            float v = acc[cf][r];
            if (z == 0)      qpb[(size_t)orow * HD + col] = f2bf(v * QSCALE);
            else if (z == 1) kpb[(size_t)orow * HD + col] = f2bf(v);
            else             vpt[(size_t)(orow >> 10) * (HD * NK) + (size_t)col * NK + (orow & 1023)] = f2bf(v);
        }
    }
}

// ---------------- aq/bk in f16 ---------------------------------------------
__global__ __launch_bounds__(256) void prep_kernel(
    const float* __restrict__ tq, const float* __restrict__ tk,
    const float* __restrict__ Wk1, const float* __restrict__ bk1,
    ushort* __restrict__ aqh, ushort* __restrict__ bkh)
{
    int gid = blockIdx.x * 256 + threadIdx.x;
    if (gid < MB * NQ * KHC) {
        int row = gid >> 5, j = gid & 31;
        aqh[gid] = f2h(tq[row * 2] * Wk1[j] + tq[row * 2 + 1] * Wk1[KHC + j] + bk1[j]);
    } else {
        int g = gid - MB * NQ * KHC;
        int row = g >> 5, j = g & 31;
        bkh[g] = f2h(tk[row * 2] * Wk1[j] + tk[row * 2 + 1] * Wk1[KHC + j]);
    }
}

// ---------------- tsum[m*2+c] = sum_k tk[m,k,c] ----------------------------
__global__ __launch_bounds__(256) void tsum_kernel(const float* __restrict__ tk, float* __restrict__ tsum)
{
    __shared__ float red[256];
    int t = threadIdx.x;
    for (int mc = 0; mc < 4; ++mc) {
        int m = mc >> 1, c = mc & 1;
        float s = 0.f;
        for (int k = t; k < NK; k += 256) s += tk[(size_t)(m * NK + k) * 2 + c];
        red[t] = s; __syncthreads();
        for (int off = 128; off > 0; off >>= 1) {
            if (t < off) red[t] += red[t + off];
            __syncthreads();
        }
        if (t == 0) tsum[mc] = red[0];
        __syncthreads();
    }
}

// ---------------- fused attention v3 ---------------------------------------
__global__ __launch_bounds__(256, 2) void attn_kernel(
    const ushort* __restrict__ qpb, const ushort* __restrict__ kpb, const ushort* __restrict__ vpt,
    const ushort* __restrict__ aqh, const ushort* __restrict__ bkh, const float* __restrict__ tk,
    const float* __restrict__ Wk2, const float* __restrict__ bk2,
    float* __restrict__ part)
{
    const int ks = blockIdx.x;
    const int qt = blockIdx.y;
    const int m  = blockIdx.z;
    const int q0 = qt * QB;
    const int kbase = ks * KL;
    const int t = threadIdx.x;
    const int wid = t >> 6;
    const int l = t & 63;
    const int g = l >> 4;
    const int c16 = l & 15;

    __shared__ ushort sK[32][264];        // bf16 K chunk [k][h*32+d]
    __shared__ ushort sVT[8][32][40];     // bf16 V^T [h][d][k]
    __shared__ ushort sText[16][40];      // bf16 ext rows: 0=tk0,1=tk1,2=ones
    __shared__ ushort sBKh[32][40];       // f16 bk chunk [k][j]
    __shared__ ushort sAQh[32][32];       // f16 aq tile [q][j]
    __shared__ ushort sW2Th[16][32];      // f16 Wk2^T*LOG2E [h][j]
    __shared__ ushort sKDh[8 * KDH];      // f16 kd [h][q][k]
    __shared__ ushort sP[4][32][40];      // bf16 P [wid][q][k]

    // ---- once-per-block ----
    for (int idx = t; idx < 512; idx += 256) {
        int h = idx >> 5, j = idx & 31;
        float v = (h < HH) ? Wk2[j * HH + h] * LOG2E : 0.f;
        sW2Th[h][j] = f2h(v);
    }
    for (int idx = t; idx < 560; idx += 256) {
        int r = 2 + idx / 40, c = idx % 40;
        sText[r][c] = (r == 2) ? (ushort)0x3F80 : (ushort)0;
    }
    {
        int q = t >> 3, j0 = (t & 7) * 4;
        uint2 v = *(const uint2*)(aqh + (size_t)(m * NQ + q0 + q) * KHC + j0);
        *(uint2*)&sAQh[q][j0] = v;
    }

    // persistent Q fragments (B-operand): [head][qfrag]
    bf16x8 qb[2][2];
    #pragma unroll
    for (int hh = 0; hh < 2; ++hh)
        #pragma unroll
        for (int qf = 0; qf < 2; ++qf)
            qb[hh][qf] = *(const bf16x8*)(qpb + (size_t)(m * NQ + q0 + qf * 16 + c16) * HD
                                              + (wid * 2 + hh) * DD + g * 8);
    const float b2l = (c16 < HH) ? bk2[c16] * LOG2E : 0.f;

    __syncthreads();
    f16x8 w2v = *(const f16x8*)&sW2Th[c16][g * 8];
    const f16x8 zero8 = {0, 0, 0, 0, 0, 0, 0, 0};

    f32x4 oacc[2][2][3];
    #pragma unroll
    for (int a = 0; a < 2; ++a)
        #pragma unroll
        for (int b = 0; b < 2; ++b)
            #pragma unroll
            for (int c = 0; c < 3; ++c)
                oacc[a][b][c] = (f32x4){0.f, 0.f, 0.f, 0.f};

    for (int ch = 0; ch < NCHUNK; ++ch) {
        const int k0 = kbase + ch * KB;
        __syncthreads();
        // ---- stage ----
        {   // K
            int row = t >> 3, seg = t & 7;
            const uint4* src = (const uint4*)(kpb + (size_t)(m * NK + k0 + row) * HD + seg * 32);
            uint4* dst = (uint4*)&sK[row][seg * 32];
            #pragma unroll
            for (int i = 0; i < 4; ++i) dst[i] = src[i];
        }
        {   // V^T
            int h = t >> 5, d = t & 31;
            const uint4* src = (const uint4*)(vpt + (size_t)m * (HD * NK) + (size_t)(h * DD + d) * NK + k0);
            uint4* dst = (uint4*)&sVT[h][d][0];
            #pragma unroll
            for (int i = 0; i < 4; ++i) { int ii = (i + t) & 3; dst[ii] = src[ii]; }
        }
        {   // bk chunk f16
            int k = t >> 3, j0 = (t & 7) * 4;
            uint2 v = *(const uint2*)(bkh + (size_t)(m * NK + k0 + k) * KHC + j0);
            *(uint2*)&sBKh[k][j0] = v;
        }
        if (t < 32) {
            float2 tv = *(const float2*)(tk + (size_t)(m * NK + k0 + t) * 2);
            sText[0][t] = f2bf(tv.x);
            sText[1][t] = f2bf(tv.y);
        }
        __syncthreads();

        // ---- kd phase: kd[k][h] via f16 MFMA, packed-f16 hidden -----------
        {
            f16x8 bkf0 = *(const f16x8*)&sBKh[c16][g * 8];
            f16x8 bkf1 = *(const f16x8*)&sBKh[16 + c16][g * 8];
            #pragma unroll
            for (int qi = 0; qi < 8; ++qi) {
                const int q = wid * 8 + qi;
                f16x8 aqv = *(const f16x8*)&sAQh[q][g * 8];
                #pragma unroll
                for (int kh = 0; kh < 2; ++kh) {
                    f16x8 d = aqv - (kh ? bkf1 : bkf0);
                    f16x8 hv = __builtin_elementwise_max(d, zero8);
                    f32x4 c = {b2l, b2l, b2l, b2l};
                    c = MFMA16(hv, w2v, c);
                    if (c16 < HH) {
                        uint2 st;
                        st.x = __builtin_bit_cast(uint, __builtin_amdgcn_cvt_pkrtz(c[0], c[1]));
                        st.y = __builtin_bit_cast(uint, __builtin_amdgcn_cvt_pkrtz(c[2], c[3]));
                        *(uint2*)&sKDh[c16 * KDH + q * KDQ + kh * 16 + g * 4] = st;
                    }
                }
            }
        }
        __syncthreads();

        // ---- per-head: S = K.Q^T with kd C-init, exp2, PV -----------------
        #pragma unroll
        for (int hh = 0; hh < 2; ++hh) {
            const int h = wid * 2 + hh;
            bf16x8 ka0 = *(const bf16x8*)&sK[c16][h * DD + g * 8];
            bf16x8 ka1 = *(const bf16x8*)&sK[16 + c16][h * DD + g * 8];
            const ushort* kdb = &sKDh[h * KDH];
            #pragma unroll
            for (int kf = 0; kf < 2; ++kf) {
                #pragma unroll
                for (int qf = 0; qf < 2; ++qf) {
                    uint2 kd2 = *(const uint2*)&kdb[(qf * 16 + c16) * KDQ + kf * 16 + g * 4];
                    f16x2 k01 = __builtin_bit_cast(f16x2, kd2.x);
                    f16x2 k23 = __builtin_bit_cast(f16x2, kd2.y);
                    f32x4 cinit = {(float)k01[0], (float)k01[1], (float)k23[0], (float)k23[1]};
                    f32x4 s = MFMA((kf ? ka1 : ka0), qb[hh][qf], cinit);
                    float p0 = EXP2(s[0]), p1 = EXP2(s[1]);
                    float p2 = EXP2(s[2]), p3 = EXP2(s[3]);
                    uint2 pk;
                    pk.x = (uint)f2bf(p0) | ((uint)f2bf(p1) << 16);
                    pk.y = (uint)f2bf(p2) | ((uint)f2bf(p3) << 16);
                    *(uint2*)&sP[wid][qf * 16 + c16][kf * 16 + g * 4] = pk;
                }
            }
            bf16x8 vb0 = *(const bf16x8*)&sVT[h][c16][g * 8];
            bf16x8 vb1 = *(const bf16x8*)&sVT[h][16 + c16][g * 8];
            bf16x8 vbt = *(const bf16x8*)&sText[c16][g * 8];
            #pragma unroll
            for (int qf = 0; qf < 2; ++qf) {
                bf16x8 pa = *(const bf16x8*)&sP[wid][qf * 16 + c16][g * 8];
                oacc[hh][qf][0] = MFMA(pa, vb0, oacc[hh][qf][0]);
                oacc[hh][qf][1] = MFMA(pa, vb1, oacc[hh][qf][1]);
                oacc[hh][qf][2] = MFMA(pa, vbt, oacc[hh][qf][2]);
            }
        }
    }

    // ---- write partials [mh][ks][q][36]: 0..31=O, 32=aT0, 33=aT1, 34=l ----
    #pragma unroll
    for (int hh = 0; hh < 2; ++hh) {
        int mh = m * HH + wid * 2 + hh;
        #pragma unroll
        for (int qf = 0; qf < 2; ++qf) {
            #pragma unroll
            for (int r = 0; r < 4; ++r) {
                int q = q0 + qf * 16 + g * 4 + r;
                size_t row = ((size_t)(mh * KSPLIT + ks) * NQ + q) * 36;
                part[row + c16]      = oacc[hh][qf][0][r];
                part[row + 16 + c16] = oacc[hh][qf][1][r];
                if (c16 < 3) part[row + 32 + c16] = oacc[hh][qf][2][r];
            }
        }
    }
}

// ---------------- combine slices + tq_new ----------------------------------
__global__ __launch_bounds__(256) void combine_kernel(
    const float* __restrict__ part, const float* __restrict__ tq,
    const float* __restrict__ Wphi, const float* __restrict__ bphi,
    const float* __restrict__ tsum,
    ushort* __restrict__ hob, float* __restrict__ tq_out)
{
    const int b = blockIdx.x;
    const int m = b >> 5;
    const int q0 = (b & 31) * 32;
    const int t = threadIdx.x;
    const int h = t >> 5, ql = t & 31;
    const int q = q0 + ql;
    const int mh = m * HH + h;

    float acc[DD] = {};
    float aT0 = 0.f, aT1 = 0.f, lsum = 0.f;
    for (int s = 0; s < KSPLIT; ++s) {
        const float* ps = part + ((size_t)(mh * KSPLIT + s) * NQ + q) * 36;
        #pragma unroll
        for (int d4 = 0; d4 < 8; ++d4) {
            float4 v = *(const float4*)(ps + d4 * 4);
            acc[d4 * 4] += v.x; acc[d4 * 4 + 1] += v.y;
            acc[d4 * 4 + 2] += v.z; acc[d4 * 4 + 3] += v.w;
        }
        aT0 += ps[32]; aT1 += ps[33]; lsum += ps[34];
    }
    const float inv = 1.f / lsum;
    ushort* ho = hob + (size_t)(m * NQ + q) * HD + h * DD;
    #pragma unroll
    for (int d8 = 0; d8 < 4; ++d8) {
        uint2 pk;
        pk.x = (uint)f2bf(acc[d8*8]*inv)     | ((uint)f2bf(acc[d8*8+1]*inv) << 16);
        pk.y = (uint)f2bf(acc[d8*8+2]*inv)   | ((uint)f2bf(acc[d8*8+3]*inv) << 16);
        uint2 pk2;
        pk2.x = (uint)f2bf(acc[d8*8+4]*inv)  | ((uint)f2bf(acc[d8*8+5]*inv) << 16);
        pk2.y = (uint)f2bf(acc[d8*8+6]*inv)  | ((uint)f2bf(acc[d8*8+7]*inv) << 16);
        *(uint2*)(ho + d8 * 8) = pk;
        *(uint2*)(ho + d8 * 8 + 4) = pk2;
    }
    const float A0 = aT0 * inv, A1 = aT1 * inv;
    const float tq0 = tq[(size_t)(m * NQ + q) * 2];
    const float tq1 = tq[(size_t)(m * NQ + q) * 2 + 1];
    const float d0 = Wphi[h * 2 + 0] * (tq0 - A0);
    const float d1 = Wphi[h * 2 + 1] * (tq1 - A1);

    __shared__ float sD[8][32][2];
    sD[h][ql][0] = d0; sD[h][ql][1] = d1;
    __syncthreads();
    if (t < 64) {
        int ql2 = t >> 1, c = t & 1;
        float s = 0.f;
        #pragma unroll
        for (int hh2 = 0; hh2 < 8; ++hh2) s += sD[hh2][ql2][c];
        int qg = q0 + ql2;
        float tqv = tq[(size_t)(m * NQ + qg) * 2 + c];
        const float invnk = 1.f / (float)NK;
        float val = tqv + s * invnk + bphi[c] * (tqv - tsum[m * 2 + c] * invnk);
        tq_out[(size_t)(m * NQ + qg) * 2 + c] = val;
    }
}

// ---------------- out = hob @ Wo + bo via MFMA -----------------------------
__global__ __launch_bounds__(256) void outproj_kernel(
    const ushort* __restrict__ hob, const ushort* __restrict__ wt,
    const float* __restrict__ bias, float* __restrict__ o)
{
    const ushort* wz = wt + (size_t)3 * 65536;
    const int r0 = blockIdx.x * 32;
    const int t = threadIdx.x;
    const int wid = t >> 6, l = t & 63, g = l >> 4, c16 = l & 15;
    const int wr = (wid >> 1) * 16, wc = (wid & 1) * 128;
    const int row = r0 + wr + c16;

    f32x4 acc[8];
    #pragma unroll
    for (int i = 0; i < 8; ++i) acc[i] = (f32x4){0.f, 0.f, 0.f, 0.f};

    for (int k0 = 0; k0 < HD; k0 += 32) {
        bf16x8 af = *(const bf16x8*)(hob + (size_t)row * HD + k0 + g * 8);
        #pragma unroll
        for (int cf = 0; cf < 8; ++cf) {
            bf16x8 bf = *(const bf16x8*)(wz + (size_t)(wc + cf * 16 + c16) * 256 + k0 + g * 8);
            acc[cf] = MFMA(af, bf, acc[cf]);
        }
    }
    #pragma unroll
    for (int cf = 0; cf < 8; ++cf) {
        int col = wc + cf * 16 + c16;
        float bv = bias[col];
        #pragma unroll
        for (int r = 0; r < 4; ++r) {
            int orow = r0 + wr + g * 4 + r;
            o[(size_t)orow * DXC + col] = acc[cf][r] + bv;
        }
    }
}

extern "C" void kernel_launch(void* const* d_in, const int* in_sizes, int n_in,
                              void* d_out, int out_size, void* d_ws, size_t ws_size,
                              hipStream_t stream)
{
    const float* xq   = (const float*)d_in[0];
    const float* xk   = (const float*)d_in[1];
    const float* xv   = (const float*)d_in[2];
    const float* tq   = (const float*)d_in[3];
    const float* tk   = (const float*)d_in[4];
    const float* Wq   = (const float*)d_in[5];
    const float* Wk   = (const float*)d_in[6];
    const float* Wv   = (const float*)d_in[7];
    const float* Wo   = (const float*)d_in[8];
    const float* bo   = (const float*)d_in[9];
    const float* Wk1  = (const float*)d_in[10];
    const float* bk1  = (const float*)d_in[11];
    const float* Wk2  = (const float*)d_in[12];
    const float* bk2  = (const float*)d_in[13];
    const float* Wphi = (const float*)d_in[14];
    const float* bphi = (const float*)d_in[15];

    float* wsf = (float*)d_ws;
    ushort* qpb = (ushort*)(wsf + QPB_F);
    ushort* kpb = (ushort*)(wsf + KPB_F);
    ushort* vpt = (ushort*)(wsf + VPT_F);
    ushort* wt  = (ushort*)(wsf + WT_F);
    ushort* aqh = (ushort*)(wsf + AQH_F);
    ushort* bkh = (ushort*)(wsf + BKH_F);
    float* ts   = wsf + TS_F;
    float* part = wsf + PART_F;
    ushort* hob = (ushort*)(wsf + HOB_F);

    float* out    = (float*)d_out;
    float* tq_out = out + (size_t)MB * NQ * HD;

    hipLaunchKernelGGL(wconv_kernel, dim3(4, 4, 4), dim3(256), 0, stream,
                       Wq, Wk, Wv, Wo, wt);
    hipLaunchKernelGGL(prep_kernel, dim3(512), dim3(256), 0, stream,
                       tq, tk, Wk1, bk1, aqh, bkh);
    hipLaunchKernelGGL(tsum_kernel, dim3(1), dim3(256), 0, stream, tk, ts);
    hipLaunchKernelGGL(projm_kernel, dim3(64, 3), dim3(256), 0, stream,
                       xq, xk, xv, wt, qpb, kpb, vpt);
    hipLaunchKernelGGL(attn_kernel, dim3(KSPLIT, NQ / QB, MB), dim3(256), 0, stream,
                       qpb, kpb, vpt, aqh, bkh, tk, Wk2, bk2, part);
    hipLaunchKernelGGL(combine_kernel, dim3(64), dim3(256), 0, stream,
                       part, tq, Wphi, bphi, ts, hob, tq_out);
    hipLaunchKernelGGL(outproj_kernel, dim3(64), dim3(256), 0, stream,
                       hob, wt, bo, out);
}

// Round 6
// 61.545 us; speedup vs baseline: 2.5733x; 1.3215x over previous
//
#include <hip/hip_runtime.h>
#include <hip/hip_bf16.h>

#define MB 2
#define NQ 1024
#define NK 1024
#define DXC 256
#define HD 256
#define HH 8
#define DD 32
#define KHC 32
#define LOG2E 1.4426950408889634f
#define QSCALE 0.25503472301046627f   // 32^-0.5 * LOG2E

#define QB 32
#define KB 32
#define KSPLIT 8
#define KL (NK / KSPLIT)      // 128
#define NCHUNK (KL / KB)      // 4

// ws layout (float offsets)
#define QPB_F   0u            // bf16 q (scaled QSCALE)  [2][1024][256]
#define KPB_F   262144u       // bf16 k
#define VPT_F   524288u       // bf16 v^T [2][256][1024]
#define WT_F    786432u       // bf16 W^T x4 mats [4][256 col][256 k]
#define AQH_F   917504u       // f16 aq [2][1024][32]
#define BKH_F   950272u       // f16 bk [2][1024][32]
#define TS_F    983040u       // f32 tsum[4] (+pad to 8)
#define TKX_F   983048u       // bf16 [2][3][1024] (tk0,tk1,ones)
#define W2T_F   986120u       // f16 [16][32] Wk2^T*LOG2E
#define PART_F  986376u       // ushort [16mh][8ks][1024q][40]
#define HOB_F   3607816u      // bf16 head_out [2][1024][256]

typedef float f32x4 __attribute__((ext_vector_type(4)));
typedef short bf16x8 __attribute__((ext_vector_type(8)));
typedef _Float16 f16x8 __attribute__((ext_vector_type(8)));
typedef _Float16 f16x2 __attribute__((ext_vector_type(2)));

#define MFMA(a, b, c)   __builtin_amdgcn_mfma_f32_16x16x32_bf16(a, b, c, 0, 0, 0)
#define MFMA16(a, b, c) __builtin_amdgcn_mfma_f32_16x16x32_f16(a, b, c, 0, 0, 0)
#define EXP2(x) exp2f(x)

// sKD geometry: [h][q][k] f16, k-stride 36, plane stride 1160
#define KDQ 36
#define KDH 1160

__device__ __forceinline__ float bf2f(uint x) {
    return __uint_as_float((x & 0xffffu) << 16);
}
__device__ __forceinline__ ushort f2bf(float f) {
    __hip_bfloat16 h = __float2bfloat16(f);
    return __builtin_bit_cast(ushort, h);
}
__device__ __forceinline__ ushort f2h(float f) {
    _Float16 h = (_Float16)f;
    return __builtin_bit_cast(ushort, h);
}

union Bf16x8 { bf16x8 v; ushort u[8]; uint d[4]; };

// ---------------- W -> W^T bf16 (4 matrices, all 256x256) ------------------
__global__ __launch_bounds__(256) void wconv_kernel(
    const float* __restrict__ Wq, const float* __restrict__ Wk,
    const float* __restrict__ Wv, const float* __restrict__ Wo,
    ushort* __restrict__ wt)
{
    const int mat = blockIdx.z;
    const float* W = (mat == 0) ? Wq : (mat == 1) ? Wk : (mat == 2) ? Wv : Wo;
    const int k0 = blockIdx.x * 64, c0 = blockIdx.y * 64;
    const int t = threadIdx.x;
    __shared__ float sW[64][65];
    #pragma unroll
    for (int i = 0; i < 4; ++i) {
        int flat = i * 1024 + t * 4;
        int r = flat >> 6, c = flat & 63;
        float4 v4 = *(const float4*)(W + (size_t)(k0 + r) * 256 + c0 + c);
        sW[r][c] = v4.x; sW[r][c + 1] = v4.y; sW[r][c + 2] = v4.z; sW[r][c + 3] = v4.w;
    }
    __syncthreads();
    #pragma unroll
    for (int i = 0; i < 4; ++i) {
        int flat = i * 1024 + t * 4;
        int cc = flat >> 6, kk = flat & 63;
        uint2 pk;
        pk.x = (uint)f2bf(sW[kk][cc])     | ((uint)f2bf(sW[kk + 1][cc]) << 16);
        pk.y = (uint)f2bf(sW[kk + 2][cc]) | ((uint)f2bf(sW[kk + 3][cc]) << 16);
        *(uint2*)(wt + (size_t)mat * 65536 + (size_t)(c0 + cc) * 256 + k0 + kk) = pk;
    }
}

// ---------------- projections via MFMA: x f32 -> q/k/v bf16 ----------------
__global__ __launch_bounds__(256) void projm_kernel(
    const float* __restrict__ xq, const float* __restrict__ xk, const float* __restrict__ xv,
    const ushort* __restrict__ wt,
    ushort* __restrict__ qpb, ushort* __restrict__ kpb, ushort* __restrict__ vpt)
{
    const int z = blockIdx.y;
    const float* x = (z == 0) ? xq : (z == 1) ? xk : xv;
    const ushort* wz = wt + (size_t)z * 65536;
    const int r0 = blockIdx.x * 32;
    const int t = threadIdx.x;
    const int wid = t >> 6, l = t & 63, g = l >> 4, c16 = l & 15;
    const int wr = (wid >> 1) * 16, wc = (wid & 1) * 128;
    const int row = r0 + wr + c16;

    __shared__ ushort sTr[256][40];   // transpose staging (z==2 only)

    f32x4 acc[8];
    #pragma unroll
    for (int i = 0; i < 8; ++i) acc[i] = (f32x4){0.f, 0.f, 0.f, 0.f};

    for (int k0 = 0; k0 < DXC; k0 += 32) {
        const float* xr = x + (size_t)row * DXC + k0 + g * 8;
        float4 a0 = *(const float4*)xr;
        float4 a1 = *(const float4*)(xr + 4);
        Bf16x8 af;
        af.d[0] = (uint)f2bf(a0.x) | ((uint)f2bf(a0.y) << 16);
        af.d[1] = (uint)f2bf(a0.z) | ((uint)f2bf(a0.w) << 16);
        af.d[2] = (uint)f2bf(a1.x) | ((uint)f2bf(a1.y) << 16);
        af.d[3] = (uint)f2bf(a1.z) | ((uint)f2bf(a1.w) << 16);
        #pragma unroll
        for (int cf = 0; cf < 8; ++cf) {
            bf16x8 bf = *(const bf16x8*)(wz + (size_t)(wc + cf * 16 + c16) * 256 + k0 + g * 8);
            acc[cf] = MFMA(af.v, bf, acc[cf]);
        }
    }
    if (z != 2) {
        #pragma unroll
        for (int cf = 0; cf < 8; ++cf) {
            #pragma unroll
            for (int r = 0; r < 4; ++r) {
                int orow = r0 + wr + g * 4 + r;
                int col = wc + cf * 16 + c16;
                float v = acc[cf][r];
                if (z == 0) qpb[(size_t)orow * HD + col] = f2bf(v * QSCALE);
                else        kpb[(size_t)orow * HD + col] = f2bf(v);
            }
        }
    } else {
        #pragma unroll
        for (int cf = 0; cf < 8; ++cf)
            #pragma unroll
            for (int r = 0; r < 4; ++r)
                sTr[wc + cf * 16 + c16][wr + g * 4 + r] = f2bf(acc[cf][r]);
        __syncthreads();
        // thread t owns column t: 64B contiguous store into v^T
        const int mq = r0 >> 10, rin = r0 & 1023;
        ushort* dst = vpt + (size_t)mq * (HD * NK) + (size_t)t * NK + rin;
        #pragma unroll
        for (int j = 0; j < 4; ++j)
            *(uint4*)(dst + j * 8) = *(const uint4*)&sTr[t][j * 8];
    }
}

// ---------------- prep: aq/bk f16, tkx, w2t, tsum --------------------------
__global__ __launch_bounds__(256) void prep_kernel(
    const float* __restrict__ tq, const float* __restrict__ tk,
    const float* __restrict__ Wk1, const float* __restrict__ bk1,
    const float* __restrict__ Wk2,
    ushort* __restrict__ aqh, ushort* __restrict__ bkh,
    ushort* __restrict__ tkx, ushort* __restrict__ w2t,
    float* __restrict__ tsum)
{
    const int t = threadIdx.x;
    const int b = blockIdx.x;
    int gid = b * 256 + t;
    if (b < 256) {
        int row = gid >> 5, j = gid & 31;
        aqh[gid] = f2h(tq[row * 2] * Wk1[j] + tq[row * 2 + 1] * Wk1[KHC + j] + bk1[j]);
    } else if (b < 512) {
        int g = gid - 65536;
        int row = g >> 5, j = g & 31;
        bkh[g] = f2h(tk[row * 2] * Wk1[j] + tk[row * 2 + 1] * Wk1[KHC + j]);
    } else if (b < 536) {
        int g = gid - 131072;            // [0, 6144)
        int mm = g / 3072, rr = (g % 3072) >> 10, kk = g & 1023;
        float v = (rr == 0) ? tk[(size_t)(mm * NK + kk) * 2]
                : (rr == 1) ? tk[(size_t)(mm * NK + kk) * 2 + 1] : 1.0f;
        tkx[g] = f2bf(v);
    } else if (b < 538) {
        int g = gid - 137216;            // [0, 512)
        int hh2 = g >> 5, jj = g & 31;
        w2t[g] = f2h(hh2 < HH ? Wk2[jj * HH + hh2] * LOG2E : 0.f);
    } else {
        const int m = b - 538;
        const int c = t & 1, kk = t >> 1;
        float s = 0.f;
        #pragma unroll
        for (int i = 0; i < 8; ++i) s += tk[(size_t)(m * NK + kk + i * 128) * 2 + c];
        __shared__ float red[256];
        red[t] = s; __syncthreads();
        for (int off = 128; off >= 2; off >>= 1) {
            if (t < off) red[t] += red[t + off];
            __syncthreads();
        }
        if (t < 2) tsum[m * 2 + t] = red[t];
    }
}

// ---------------- fused attention v4: direct-global, dbuf kd ---------------
__global__ __launch_bounds__(256, 3) void attn_kernel(
    const ushort* __restrict__ qpb, const ushort* __restrict__ kpb, const ushort* __restrict__ vpt,
    const ushort* __restrict__ aqh, const ushort* __restrict__ bkh,
    const ushort* __restrict__ tkx, const ushort* __restrict__ w2t,
    const float* __restrict__ bk2,
    ushort* __restrict__ part)
{
    const int ks = blockIdx.x;
    const int qt = blockIdx.y;
    const int m  = blockIdx.z;
    const int q0 = qt * QB;
    const int kbase = ks * KL;
    const int t = threadIdx.x;
    const int wid = t >> 6;
    const int l = t & 63;
    const int g = l >> 4;
    const int c16 = l & 15;

    __shared__ ushort sKD[2][8 * KDH];   // f16 kd [h][q][k], double-buffered
    __shared__ ushort sP[4][32][40];     // bf16 P [wid][q][k]

    // ---- register hoists ----
    f16x8 w2v = *(const f16x8*)(w2t + c16 * 32 + g * 8);
    const float b2l = (c16 < HH) ? bk2[c16] * LOG2E : 0.f;
    const f16x8 zero8 = {0, 0, 0, 0, 0, 0, 0, 0};

    bf16x8 qb[2][2];
    #pragma unroll
    for (int hh = 0; hh < 2; ++hh)
        #pragma unroll
        for (int qf = 0; qf < 2; ++qf)
            qb[hh][qf] = *(const bf16x8*)(qpb + (size_t)(m * NQ + q0 + qf * 16 + c16) * HD
                                              + (wid * 2 + hh) * DD + g * 8);
    f16x8 aqv[8];
    #pragma unroll
    for (int qi = 0; qi < 8; ++qi)
        aqv[qi] = *(const f16x8*)(aqh + (size_t)(m * NQ + q0 + wid * 8 + qi) * KHC + g * 8);

    f32x4 oacc[2][2][3];
    #pragma unroll
    for (int a = 0; a < 2; ++a)
        #pragma unroll
        for (int b = 0; b < 2; ++b)
            #pragma unroll
            for (int c = 0; c < 3; ++c)
                oacc[a][b][c] = (f32x4){0.f, 0.f, 0.f, 0.f};

    for (int ch = 0; ch < NCHUNK; ++ch) {
        const int k0 = kbase + ch * KB;
        const int buf = ch & 1;
        // ---- kd phase -> sKD[buf] ----
        {
            f16x8 bkf0 = *(const f16x8*)(bkh + (size_t)(m * NK + k0 + c16) * KHC + g * 8);
            f16x8 bkf1 = *(const f16x8*)(bkh + (size_t)(m * NK + k0 + 16 + c16) * KHC + g * 8);
            #pragma unroll
            for (int qi = 0; qi < 8; ++qi) {
                const int q = wid * 8 + qi;
                #pragma unroll
                for (int kh = 0; kh < 2; ++kh) {
                    f16x8 d = aqv[qi] - (kh ? bkf1 : bkf0);
                    f16x8 hv = __builtin_elementwise_max(d, zero8);
                    f32x4 c = {b2l, b2l, b2l, b2l};
                    c = MFMA16(hv, w2v, c);
                    if (c16 < HH) {
                        uint2 st;
                        st.x = __builtin_bit_cast(uint, __builtin_amdgcn_cvt_pkrtz(c[0], c[1]));
                        st.y = __builtin_bit_cast(uint, __builtin_amdgcn_cvt_pkrtz(c[2], c[3]));
                        *(uint2*)&sKD[buf][c16 * KDH + q * KDQ + kh * 16 + g * 4] = st;
                    }
                }
            }
        }
        __syncthreads();

        // ---- QK (kd C-init) + exp2 + PV, all operands direct from L2 ----
        #pragma unroll
        for (int hh = 0; hh < 2; ++hh) {
            const int h = wid * 2 + hh;
            bf16x8 ka0 = *(const bf16x8*)(kpb + (size_t)(m * NK + k0 + c16) * HD + h * DD + g * 8);
            bf16x8 ka1 = *(const bf16x8*)(kpb + (size_t)(m * NK + k0 + 16 + c16) * HD + h * DD + g * 8);
            const ushort* kdb = &sKD[buf][h * KDH];
            #pragma unroll
            for (int kf = 0; kf < 2; ++kf) {
                #pragma unroll
                for (int qf = 0; qf < 2; ++qf) {
                    uint2 kd2 = *(const uint2*)&kdb[(qf * 16 + c16) * KDQ + kf * 16 + g * 4];
                    f16x2 k01 = __builtin_bit_cast(f16x2, kd2.x);
                    f16x2 k23 = __builtin_bit_cast(f16x2, kd2.y);
                    f32x4 cinit = {(float)k01[0], (float)k01[1], (float)k23[0], (float)k23[1]};
                    f32x4 s = MFMA((kf ? ka1 : ka0), qb[hh][qf], cinit);
                    float p0 = EXP2(s[0]), p1 = EXP2(s[1]);
                    float p2 = EXP2(s[2]), p3 = EXP2(s[3]);
                    uint2 pk;
                    pk.x = (uint)f2bf(p0) | ((uint)f2bf(p1) << 16);
                    pk.y = (uint)f2bf(p2) | ((uint)f2bf(p3) << 16);
                    *(uint2*)&sP[wid][qf * 16 + c16][kf * 16 + g * 4] = pk;
                }
            }
            bf16x8 vb0 = *(const bf16x8*)(vpt + (size_t)m * (HD * NK) + (size_t)(h * DD + c16) * NK + k0 + g * 8);
            bf16x8 vb1 = *(const bf16x8*)(vpt + (size_t)m * (HD * NK) + (size_t)(h * DD + 16 + c16) * NK + k0 + g * 8);
            bf16x8 vbt = *(const bf16x8*)(tkx + (size_t)m * 3072 + (size_t)(c16 < 2 ? c16 : 2) * NK + k0 + g * 8);
            #pragma unroll
            for (int qf = 0; qf < 2; ++qf) {
                bf16x8 pa = *(const bf16x8*)&sP[wid][qf * 16 + c16][g * 8];
                oacc[hh][qf][0] = MFMA(pa, vb0, oacc[hh][qf][0]);
                oacc[hh][qf][1] = MFMA(pa, vb1, oacc[hh][qf][1]);
                oacc[hh][qf][2] = MFMA(pa, vbt, oacc[hh][qf][2]);
            }
        }
    }

    // ---- write partials [mh][ks][q] 40 ushorts: O bf16 x32, aT bf16 x2, l f32
    #pragma unroll
    for (int hh = 0; hh < 2; ++hh) {
        int mh = m * HH + wid * 2 + hh;
        #pragma unroll
        for (int qf = 0; qf < 2; ++qf) {
            #pragma unroll
            for (int r = 0; r < 4; ++r) {
                int q = q0 + qf * 16 + g * 4 + r;
                ushort* pb = part + ((size_t)(mh * KSPLIT + ks) * NQ + q) * 40;
                pb[c16]      = f2bf(oacc[hh][qf][0][r]);
                pb[16 + c16] = f2bf(oacc[hh][qf][1][r]);
                float e = oacc[hh][qf][2][r];
                if (c16 < 2) pb[32 + c16] = f2bf(e);
                else if (c16 == 2) *(float*)(pb + 34) = e;
            }
        }
    }
}

// ---------------- combine slices + tq_new ----------------------------------
__global__ __launch_bounds__(256) void combine_kernel(
    const ushort* __restrict__ part, const float* __restrict__ tq,
    const float* __restrict__ Wphi, const float* __restrict__ bphi,
    const float* __restrict__ tsum,
    ushort* __restrict__ hob, float* __restrict__ tq_out)
{
    const int b = blockIdx.x;            // 128 blocks
    const int m = b >> 6;
    const int q0 = (b & 63) * 16;
    const int t = threadIdx.x;
    const int h = t >> 5;                // 0..7
    const int dgrp = (t >> 4) & 1;       // which 16 of the 32 O dims
    const int qloc = t & 15;
    const int q = q0 + qloc;
    const int mh = m * HH + h;

    float accO[16] = {};
    float aT = 0.f, lsum = 0.f;
    for (int s = 0; s < KSPLIT; ++s) {
        const ushort* ps = part + ((size_t)(mh * KSPLIT + s) * NQ + q) * 40;
        uint4 v0 = *(const uint4*)(ps + dgrp * 16);
        uint4 v1 = *(const uint4*)(ps + dgrp * 16 + 8);
        accO[0] += bf2f(v0.x); accO[1] += bf2f(v0.x >> 16);
        accO[2] += bf2f(v0.y); accO[3] += bf2f(v0.y >> 16);
        accO[4] += bf2f(v0.z); accO[5] += bf2f(v0.z >> 16);
        accO[6] += bf2f(v0.w); accO[7] += bf2f(v0.w >> 16);
        accO[8] += bf2f(v1.x); accO[9] += bf2f(v1.x >> 16);
        accO[10] += bf2f(v1.y); accO[11] += bf2f(v1.y >> 16);
        accO[12] += bf2f(v1.z); accO[13] += bf2f(v1.z >> 16);
        accO[14] += bf2f(v1.w); accO[15] += bf2f(v1.w >> 16);
        uint at = *(const uint*)(ps + 32);
        aT += bf2f(dgrp == 0 ? at : (at >> 16));
        lsum += *(const float*)(ps + 34);
    }
    const float inv = 1.f / lsum;
    {
        uint dd[8];
        #pragma unroll
        for (int i = 0; i < 8; ++i)
            dd[i] = (uint)f2bf(accO[2 * i] * inv) | ((uint)f2bf(accO[2 * i + 1] * inv) << 16);
        ushort* ho = hob + (size_t)(m * NQ + q) * HD + h * DD + dgrp * 16;
        *(uint4*)ho       = (uint4){dd[0], dd[1], dd[2], dd[3]};
        *(uint4*)(ho + 8) = (uint4){dd[4], dd[5], dd[6], dd[7]};
    }
    const float A = aT * inv;
    const float tqc = tq[(size_t)(m * NQ + q) * 2 + dgrp];
    const float dphi = Wphi[h * 2 + dgrp] * (tqc - A);

    __shared__ float sD[8][16][2];
    sD[h][qloc][dgrp] = dphi;
    __syncthreads();
    if (t < 32) {
        int ql2 = t >> 1, c = t & 1;
        float s = 0.f;
        #pragma unroll
        for (int hh2 = 0; hh2 < 8; ++hh2) s += sD[hh2][ql2][c];
        int qg = q0 + ql2;
        float tqv = tq[(size_t)(m * NQ + qg) * 2 + c];
        const float invnk = 1.f / (float)NK;
        float val = tqv + s * invnk + bphi[c] * (tqv - tsum[m * 2 + c] * invnk);
        tq_out[(size_t)(m * NQ + qg) * 2 + c] = val;
    }
}

// ---------------- out = hob @ Wo + bo via MFMA -----------------------------
__global__ __launch_bounds__(256) void outproj_kernel(
    const ushort* __restrict__ hob, const ushort* __restrict__ wt,
    const float* __restrict__ bias, float* __restrict__ o)
{
    const ushort* wz = wt + (size_t)3 * 65536;
    const int r0 = blockIdx.x * 32;
    const int t = threadIdx.x;
    const int wid = t >> 6, l = t & 63, g = l >> 4, c16 = l & 15;
    const int wr = (wid >> 1) * 16, wc = (wid & 1) * 128;
    const int row = r0 + wr + c16;

    f32x4 acc[8];
    #pragma unroll
    for (int i = 0; i < 8; ++i) acc[i] = (f32x4){0.f, 0.f, 0.f, 0.f};

    for (int k0 = 0; k0 < HD; k0 += 32) {
        bf16x8 af = *(const bf16x8*)(hob + (size_t)row * HD + k0 + g * 8);
        #pragma unroll
        for (int cf = 0; cf < 8; ++cf) {
            bf16x8 bf = *(const bf16x8*)(wz + (size_t)(wc + cf * 16 + c16) * 256 + k0 + g * 8);
            acc[cf] = MFMA(af, bf, acc[cf]);
        }
    }
    #pragma unroll
    for (int cf = 0; cf < 8; ++cf) {
        int col = wc + cf * 16 + c16;
        float bv = bias[col];
        #pragma unroll
        for (int r = 0; r < 4; ++r) {
            int orow = r0 + wr + g * 4 + r;
            o[(size_t)orow * DXC + col] = acc[cf][r] + bv;
        }
    }
}

extern "C" void kernel_launch(void* const* d_in, const int* in_sizes, int n_in,
                              void* d_out, int out_size, void* d_ws, size_t ws_size,
                              hipStream_t stream)
{
    const float* xq   = (const float*)d_in[0];
    const float* xk   = (const float*)d_in[1];
    const float* xv   = (const float*)d_in[2];
    const float* tq   = (const float*)d_in[3];
    const float* tk   = (const float*)d_in[4];
    const float* Wq   = (const float*)d_in[5];
    const float* Wk   = (const float*)d_in[6];
    const float* Wv   = (const float*)d_in[7];
    const float* Wo   = (const float*)d_in[8];
    const float* bo   = (const float*)d_in[9];
    const float* Wk1  = (const float*)d_in[10];
    const float* bk1  = (const float*)d_in[11];
    const float* Wk2  = (const float*)d_in[12];
    const float* bk2  = (const float*)d_in[13];
    const float* Wphi = (const float*)d_in[14];
    const float* bphi = (const float*)d_in[15];

    float* wsf = (float*)d_ws;
    ushort* qpb = (ushort*)(wsf + QPB_F);
    ushort* kpb = (ushort*)(wsf + KPB_F);
    ushort* vpt = (ushort*)(wsf + VPT_F);
    ushort* wt  = (ushort*)(wsf + WT_F);
    ushort* aqh = (ushort*)(wsf + AQH_F);
    ushort* bkh = (ushort*)(wsf + BKH_F);
    float* ts   = wsf + TS_F;
    ushort* tkx = (ushort*)(wsf + TKX_F);
    ushort* w2t = (ushort*)(wsf + W2T_F);
    ushort* part = (ushort*)(wsf + PART_F);
    ushort* hob = (ushort*)(wsf + HOB_F);

    float* out    = (float*)d_out;
    float* tq_out = out + (size_t)MB * NQ * HD;

    hipLaunchKernelGGL(wconv_kernel, dim3(4, 4, 4), dim3(256), 0, stream,
                       Wq, Wk, Wv, Wo, wt);
    hipLaunchKernelGGL(prep_kernel, dim3(540), dim3(256), 0, stream,
                       tq, tk, Wk1, bk1, Wk2, aqh, bkh, tkx, w2t, ts);
    hipLaunchKernelGGL(projm_kernel, dim3(64, 3), dim3(256), 0, stream,
                       xq, xk, xv, wt, qpb, kpb, vpt);
    hipLaunchKernelGGL(attn_kernel, dim3(KSPLIT, NQ / QB, MB), dim3(256), 0, stream,
                       qpb, kpb, vpt, aqh, bkh, tkx, w2t, bk2, part);
    hipLaunchKernelGGL(combine_kernel, dim3(128), dim3(256), 0, stream,
                       part, tq, Wphi, bphi, ts, hob, tq_out);
    hipLaunchKernelGGL(outproj_kernel, dim3(64), dim3(256), 0, stream,
                       hob, wt, bo, out);
}